// Round 5
// baseline (268.293 us; speedup 1.0000x reference)
//
#include <hip/hip_runtime.h>

typedef unsigned short u16;
typedef __attribute__((ext_vector_type(8))) short bh8;     // 8 bf16 MFMA A/B frag
typedef __attribute__((ext_vector_type(4))) float f4;      // MFMA C/D frag / float4
typedef __attribute__((ext_vector_type(4))) unsigned short us4;

#define T_SEQ 2048
#define NHEADS 16
#define DHEAD 64
#define WIN 256

__device__ __forceinline__ float bf2f(u16 u) {
  union { unsigned int i; float f; } v; v.i = ((unsigned int)u) << 16; return v.f;
}
__device__ __forceinline__ u16 f2bf(float f) {
  unsigned int u = __float_as_uint(f);
  u = u + 0x7fffu + ((u >> 16) & 1u);   // RNE
  return (u16)(u >> 16);
}
__device__ __forceinline__ void async16(const void* g, void* l) {
  void* gv = const_cast<void*>(g);
  __builtin_amdgcn_global_load_lds(
      (__attribute__((address_space(1))) void*)gv,
      (__attribute__((address_space(3))) void*)l, 16, 0, 0);
}

// ---------------- dtype detect: 1 if input is plausibly fp32, else 0 (bf16) ----------
__global__ void detect_dtype(const void* x, int* flag) {
  if (threadIdx.x == 0 && blockIdx.x == 0) {
    const float* xf = (const float*)x;
    int ok = 1;
    for (int i = 0; i < 128; ++i) {
      float v = xf[i];
      float a = fabsf(v);
      if (!(a < 64.f)) { ok = 0; break; }
      if (!(v == 0.f || a > 1e-30f)) { ok = 0; break; }
    }
    *flag = ok;
  }
}

// ---------------- x convert: fp32-or-bf16 (per flag) -> canonical bf16 --------------
__global__ void xconv(const void* __restrict__ in, u16* __restrict__ out,
                      const int* __restrict__ flag, int n8) {
  const int i = blockIdx.x * 256 + threadIdx.x;
  if (i >= n8) return;
  const size_t e = (size_t)i * 8;
  if (*flag) {
    const float* f = (const float*)in;
    us4 o0, o1;
    #pragma unroll
    for (int u = 0; u < 4; ++u) { o0[u] = f2bf(f[e + u]); o1[u] = f2bf(f[e + 4 + u]); }
    *(us4*)&out[e] = o0; *(us4*)&out[e + 4] = o1;
  } else {
    *(us4*)&out[e]     = *(const us4*)&((const u16*)in)[e];
    *(us4*)&out[e + 4] = *(const us4*)&((const u16*)in)[e + 4];
  }
}

// ---------------- transpose+convert: in (R x C, fp32-or-bf16 per flag) -> bf16 (C x R) ----
__global__ void transpose_conv(const void* __restrict__ in, u16* __restrict__ out,
                               int R, int C, const int* __restrict__ flag) {
  __shared__ alignas(16) u16 tile[32][33];
  const int isf = *flag;
  const int tx = threadIdx.x, ty = threadIdx.y;
  const int x  = blockIdx.x * 32 + tx;
  const int y0 = blockIdx.y * 32;
  #pragma unroll
  for (int i = ty; i < 32; i += 8) {
    u16 v;
    if (isf) v = f2bf(((const float*)in)[(size_t)(y0 + i) * C + x]);
    else     v = ((const u16*)in)[(size_t)(y0 + i) * C + x];
    tile[i][tx] = v;
  }
  __syncthreads();
  const int ox  = y0 + tx;
  const int oy0 = blockIdx.x * 32;
  #pragma unroll
  for (int i = ty; i < 32; i += 8)
    out[(size_t)(oy0 + i) * R + ox] = tile[tx][i];
}

// ---------------- bf16 GEMM, C[M,N] = A[M,K(lda)] * Bt[N,K]^T ----------------
// m97 structure: global_load_lds width-16 staging + XOR chunk swizzle.
// LDS slot for row R (0..127), chunk c (0..3, 8 u16 each): byte R*64 + c*16.
// Slot (R,c) holds GLOBAL chunk c ^ ((R>>1)&3)  -> fragment reads are 2-way max.
template<bool ADYN, bool CDYN>
__global__ __launch_bounds__(256) void gemm_bt(
    const void* __restrict__ A, const u16* __restrict__ Bt,
    void* __restrict__ C, int N, int K, int lda, int ldc,
    const int* __restrict__ flag)
{
  __shared__ alignas(16) u16 As[128 * 32];
  __shared__ alignas(16) u16 Bs[128 * 32];

  const int isf  = ADYN ? *flag : 0;
  const int tid  = threadIdx.x;
  const int lane = tid & 63;
  const int w    = tid >> 6;
  const int wm   = (w >> 1) * 64;
  const int wn   = (w & 1) * 64;
  const int quad = lane >> 4;
  const int l16  = lane & 15;
  const int row0 = blockIdx.y * 128;
  const int col0 = blockIdx.x * 128;

  f4 acc[4][4] = {};

  // staging: thread t -> row t>>2, LDS chunk t&3, GLOBAL chunk (t&3)^((t>>3)&3)
  const int srow = tid >> 2;
  const int scol = ((tid & 3) ^ ((tid >> 3) & 3)) * 8;
  const size_t aoff0 = (size_t)(row0 + srow) * lda + scol;
  const size_t aoff1 = (size_t)(row0 + 64 + srow) * lda + scol;
  const u16* gB0 = Bt + (size_t)(col0 + srow) * K + scol;
  const u16* gB1 = Bt + (size_t)(col0 + 64 + srow) * K + scol;
  u16* lA0 = As + tid * 8;
  u16* lA1 = As + 2048 + tid * 8;
  u16* lB0 = Bs + tid * 8;
  u16* lB1 = Bs + 2048 + tid * 8;

  const bool af32 = ADYN && isf;
  const int csw = (quad ^ ((l16 >> 1) & 3)) * 8;   // fragment-read chunk offset

  for (int k0 = 0; k0 < K; k0 += 32) {
    if (af32) {
      // fp32 A: register staging + convert (fallback path)
      const float* Af = (const float*)A;
      f4 u00 = *(const f4*)(Af + aoff0 + k0);
      f4 u01 = *(const f4*)(Af + aoff0 + k0 + 4);
      f4 u10 = *(const f4*)(Af + aoff1 + k0);
      f4 u11 = *(const f4*)(Af + aoff1 + k0 + 4);
      bh8 a0, a1;
      #pragma unroll
      for (int u = 0; u < 4; ++u) {
        a0[u]     = (short)f2bf(u00[u]);
        a0[u + 4] = (short)f2bf(u01[u]);
        a1[u]     = (short)f2bf(u10[u]);
        a1[u + 4] = (short)f2bf(u11[u]);
      }
      __syncthreads();
      *(bh8*)lA0 = a0; *(bh8*)lA1 = a1;
      async16(gB0 + k0, lB0);
      async16(gB1 + k0, lB1);
    } else {
      const u16* A16 = (const u16*)A;
      __syncthreads();               // prev-iter LDS reads complete before overwrite
      async16(A16 + aoff0 + k0, lA0);
      async16(A16 + aoff1 + k0, lA1);
      async16(gB0 + k0, lB0);
      async16(gB1 + k0, lB1);
    }
    __builtin_amdgcn_s_waitcnt(0);   // drain DMA before barrier
    __syncthreads();

    bh8 af[4], bf[4];
    #pragma unroll
    for (int i = 0; i < 4; ++i)
      af[i] = *(const bh8*)(As + (wm + i * 16 + l16) * 32 + csw);
    #pragma unroll
    for (int j = 0; j < 4; ++j)
      bf[j] = *(const bh8*)(Bs + (wn + j * 16 + l16) * 32 + csw);
    #pragma unroll
    for (int i = 0; i < 4; ++i)
      #pragma unroll
      for (int j = 0; j < 4; ++j)
        acc[i][j] = __builtin_amdgcn_mfma_f32_16x16x32_bf16(af[i], bf[j], acc[i][j], 0, 0, 0);
  }

  const bool cf32 = CDYN && (*flag);
  #pragma unroll
  for (int i = 0; i < 4; ++i) {
    #pragma unroll
    for (int j = 0; j < 4; ++j) {
      const int rb = row0 + wm + i * 16 + quad * 4;
      const int cc = col0 + wn + j * 16 + l16;
      #pragma unroll
      for (int r = 0; r < 4; ++r) {
        if (cf32) ((float*)C)[(size_t)(rb + r) * ldc + cc] = acc[i][j][r];
        else      ((u16*)C)[(size_t)(rb + r) * ldc + cc]   = f2bf(acc[i][j][r]);
      }
    }
  }
}

// ---------------- MFMA flash-style sliding-window attention ----------------
// qkv: [B*T, 3072] bf16 (q +0, k +1024, v +2048; head h at +h*64).
// Output in-place into the q-channel. Per block: 64 queries of one (b,h);
// 5 key tiles of 64; online softmax.
__global__ __launch_bounds__(256) void attn_mfma(u16* __restrict__ qkv)
{
  __shared__ alignas(16) u16 Qs[64 * 72];
  __shared__ alignas(16) u16 Kt[64 * 72];
  __shared__ alignas(16) u16 Vt[64 * 72];   // (d,k): d*72 + ((k>>3)^(d>>3))*8 + (k&7)
  __shared__ alignas(16) u16 Ps[64 * 72];   // (q,k): q*72 + ((k>>3)^((q>>3)&1))*8 + (k&7)

  const int tid  = threadIdx.x;
  const int lane = tid & 63;
  const int w    = tid >> 6;
  const int quad = lane >> 4;
  const int l16  = lane & 15;
  const int qb = blockIdx.x, h = blockIdx.y, b = blockIdx.z;
  const int qs = qb * 64;

  const u16* base = qkv + (size_t)b * T_SEQ * 3072 + h * 64;

  const int c8  = (tid & 7) * 8;
  const int r0s = tid >> 3;
  #pragma unroll
  for (int r = r0s; r < 64; r += 32)
    *(bh8*)&Qs[r * 72 + c8] = *(const bh8*)&base[(size_t)(qs + r) * 3072 + c8];

  f4 Oc[4] = {};
  float mst[4] = {-1e30f, -1e30f, -1e30f, -1e30f};
  float lst[4] = {0.f, 0.f, 0.f, 0.f};

  const int tmin = (qb >= 4) ? 0 : (4 - qb);

  for (int t = tmin; t < 5; ++t) {
    const int kt0 = qs - 256 + t * 64;
    __syncthreads();

    #pragma unroll
    for (int r = r0s; r < 64; r += 32) {
      *(bh8*)&Kt[r * 72 + c8] =
          *(const bh8*)&base[(size_t)(kt0 + r) * 3072 + 1024 + c8];
      bh8 v = *(const bh8*)&base[(size_t)(kt0 + r) * 3072 + 2048 + c8];
      const int kc = r >> 3, ki = r & 7;
      #pragma unroll
      for (int u = 0; u < 8; ++u) {
        const int d = c8 + u;
        Vt[d * 72 + ((kc ^ (d >> 3)) << 3) + ki] = (u16)v[u];
      }
    }
    __syncthreads();

    const int qrow = (w * 16 + l16) * 72;
    bh8 qa0 = *(const bh8*)&Qs[qrow + quad * 8];
    bh8 qa1 = *(const bh8*)&Qs[qrow + 32 + quad * 8];
    f4 S[4];
    #pragma unroll
    for (int kb = 0; kb < 4; ++kb) {
      const int krow = (kb * 16 + l16) * 72;
      bh8 kf0 = *(const bh8*)&Kt[krow + quad * 8];
      bh8 kf1 = *(const bh8*)&Kt[krow + 32 + quad * 8];
      f4 s = {};
      s = __builtin_amdgcn_mfma_f32_16x16x32_bf16(qa0, kf0, s, 0, 0, 0);
      s = __builtin_amdgcn_mfma_f32_16x16x32_bf16(qa1, kf1, s, 0, 0, 0);
      S[kb] = s;
    }

    const int iq0 = qs + w * 16 + quad * 4;
    float tmax[4] = {-1e30f, -1e30f, -1e30f, -1e30f};
    #pragma unroll
    for (int kb = 0; kb < 4; ++kb) {
      const int j = kt0 + kb * 16 + l16;
      #pragma unroll
      for (int rr = 0; rr < 4; ++rr) {
        const int i = iq0 + rr;
        float s = S[kb][rr] * 0.125f;
        const bool ok = (j <= i) && (j > i - WIN);
        s = ok ? s : -1e30f;
        S[kb][rr] = s;
        tmax[rr] = fmaxf(tmax[rr], s);
      }
    }
    #pragma unroll
    for (int off = 1; off < 16; off <<= 1)
      #pragma unroll
      for (int rr = 0; rr < 4; ++rr)
        tmax[rr] = fmaxf(tmax[rr], __shfl_xor(tmax[rr], off));

    float alpha[4], rsum[4];
    #pragma unroll
    for (int rr = 0; rr < 4; ++rr) {
      const float mnew = fmaxf(mst[rr], tmax[rr]);
      alpha[rr] = __expf(mst[rr] - mnew);
      mst[rr] = mnew;
      rsum[rr] = 0.f;
    }

    const int swq = quad >> 1;
    #pragma unroll
    for (int kb = 0; kb < 4; ++kb) {
      const int kc = kb * 2 + (l16 >> 3);
      const int ki = l16 & 7;
      #pragma unroll
      for (int rr = 0; rr < 4; ++rr) {
        const float sv = S[kb][rr];
        const float p = (sv > -0.5e30f) ? __expf(sv - mst[rr]) : 0.f;
        rsum[rr] += p;
        const int q = w * 16 + quad * 4 + rr;
        Ps[q * 72 + ((kc ^ swq) << 3) + ki] = f2bf(p);
      }
    }
    #pragma unroll
    for (int off = 1; off < 16; off <<= 1)
      #pragma unroll
      for (int rr = 0; rr < 4; ++rr)
        rsum[rr] += __shfl_xor(rsum[rr], off);
    #pragma unroll
    for (int rr = 0; rr < 4; ++rr)
      lst[rr] = lst[rr] * alpha[rr] + rsum[rr];

    #pragma unroll
    for (int db = 0; db < 4; ++db)
      #pragma unroll
      for (int rr = 0; rr < 4; ++rr)
        Oc[db][rr] *= alpha[rr];

    {
      const int q = w * 16 + l16;
      const int sw = (q >> 3) & 1;
      bh8 pa0 = *(const bh8*)&Ps[q * 72 + (((0 + quad) ^ sw) << 3)];
      bh8 pa1 = *(const bh8*)&Ps[q * 72 + (((4 + quad) ^ sw) << 3)];
      #pragma unroll
      for (int db = 0; db < 4; ++db) {
        const int d = db * 16 + l16;
        const int dsw = d >> 3;
        bh8 vb0 = *(const bh8*)&Vt[d * 72 + (((0 + quad) ^ dsw) << 3)];
        bh8 vb1 = *(const bh8*)&Vt[d * 72 + (((4 + quad) ^ dsw) << 3)];
        Oc[db] = __builtin_amdgcn_mfma_f32_16x16x32_bf16(pa0, vb0, Oc[db], 0, 0, 0);
        Oc[db] = __builtin_amdgcn_mfma_f32_16x16x32_bf16(pa1, vb1, Oc[db], 0, 0, 0);
      }
    }
  }

  u16* obase = (u16*)base;
  #pragma unroll
  for (int rr = 0; rr < 4; ++rr) {
    const int i = qs + w * 16 + quad * 4 + rr;
    const float inv = 1.f / lst[rr];
    #pragma unroll
    for (int db = 0; db < 4; ++db)
      obase[(size_t)i * 3072 + db * 16 + l16] = f2bf(Oc[db][rr] * inv);
  }
}

// ---------------- launcher ----------------
extern "C" void kernel_launch(void* const* d_in, const int* in_sizes, int n_in,
                              void* d_out, int out_size, void* d_ws, size_t ws_size,
                              hipStream_t stream) {
  const void* x     = d_in[0];   // [8192, 1024]  fp32 or bf16 (auto-detected)
  const void* w_qkv = d_in[1];   // [1024, 3072]
  const void* w_out = d_in[2];   // [1024, 1024]

  const size_t SZ_QKV  = (size_t)8192 * 3072 * 2;
  const size_t SZ_XBF  = (size_t)8192 * 1024 * 2;
  const size_t SZ_WQ   = (size_t)3072 * 1024 * 2;
  const size_t SZ_WO   = (size_t)1024 * 1024 * 2;

  char* p = (char*)d_ws;
  u16* qkv   = (u16*)p; p += SZ_QKV;
  u16* wqkvT = (u16*)p; p += SZ_WQ;
  u16* woutT = (u16*)p; p += SZ_WO;
  int* flag  = (int*)p; p += 16;
  u16* xbf   = (u16*)p;
  const bool have_x = ws_size >= (SZ_QKV + SZ_WQ + SZ_WO + 16 + SZ_XBF);

  detect_dtype<<<1, 64, 0, stream>>>(x, flag);

  dim3 tb(32, 8);
  transpose_conv<<<dim3(96, 32), tb, 0, stream>>>(w_qkv, wqkvT, 1024, 3072, flag);
  transpose_conv<<<dim3(32, 32), tb, 0, stream>>>(w_out, woutT, 1024, 1024, flag);

  if (have_x) {
    xconv<<<dim3(4096), 256, 0, stream>>>(x, xbf, flag, 1048576);
    gemm_bt<false, false><<<dim3(24, 64), 256, 0, stream>>>(
        xbf, wqkvT, qkv, 3072, 1024, 1024, 3072, flag);
  } else {
    gemm_bt<true, false><<<dim3(24, 64), 256, 0, stream>>>(
        x, wqkvT, qkv, 3072, 1024, 1024, 3072, flag);
  }

  attn_mfma<<<dim3(32, NHEADS, 4), 256, 0, stream>>>(qkv);

  gemm_bt<false, true><<<dim3(8, 64), 256, 0, stream>>>(
      qkv, woutT, d_out, 1024, 1024, 3072, 1024, flag);
}

// Round 6
// 239.272 us; speedup vs baseline: 1.1213x; 1.1213x over previous
//
#include <hip/hip_runtime.h>

typedef unsigned short u16;
typedef __attribute__((ext_vector_type(8))) short bh8;     // 8 bf16 MFMA A/B frag
typedef __attribute__((ext_vector_type(4))) float f4;      // MFMA C/D frag / float4
typedef __attribute__((ext_vector_type(4))) unsigned short us4;

#define T_SEQ 2048
#define NHEADS 16
#define DHEAD 64
#define WIN 256

__device__ __forceinline__ float bf2f(u16 u) {
  union { unsigned int i; float f; } v; v.i = ((unsigned int)u) << 16; return v.f;
}
__device__ __forceinline__ u16 f2bf(float f) {
  unsigned int u = __float_as_uint(f);
  u = u + 0x7fffu + ((u >> 16) & 1u);   // RNE
  return (u16)(u >> 16);
}
__device__ __forceinline__ void async16(const void* g, void* l) {
  void* gv = const_cast<void*>(g);
  __builtin_amdgcn_global_load_lds(
      (__attribute__((address_space(1))) void*)gv,
      (__attribute__((address_space(3))) void*)l, 16, 0, 0);
}

// ---------------- dtype detect: 1 if input is plausibly fp32, else 0 (bf16) ----------
__global__ void detect_dtype(const void* x, int* flag) {
  if (threadIdx.x == 0 && blockIdx.x == 0) {
    const float* xf = (const float*)x;
    int ok = 1;
    for (int i = 0; i < 128; ++i) {
      float v = xf[i];
      float a = fabsf(v);
      if (!(a < 64.f)) { ok = 0; break; }
      if (!(v == 0.f || a > 1e-30f)) { ok = 0; break; }
    }
    *flag = ok;
  }
}

// ---------------- fused prep: xconv + transpose(w_qkv) + transpose(w_out) ------------
// blocks [0,4096): xconv 8 elems/thread; [4096,7168): w_qkv tiles; [7168,8192): w_out.
__global__ __launch_bounds__(256) void prep(
    const void* __restrict__ x, const void* __restrict__ w_qkv,
    const void* __restrict__ w_out, u16* __restrict__ xbf,
    u16* __restrict__ wqkvT, u16* __restrict__ woutT,
    const int* __restrict__ flag, int have_x)
{
  const int bid = blockIdx.x;
  const int tid = threadIdx.x;
  const int isf = *flag;

  if (bid < 4096) {                       // ---- xconv ----
    if (!have_x) return;
    const size_t e = ((size_t)bid * 256 + tid) * 8;
    if (isf) {
      const float* f = (const float*)x;
      us4 o0, o1;
      #pragma unroll
      for (int u = 0; u < 4; ++u) { o0[u] = f2bf(f[e + u]); o1[u] = f2bf(f[e + 4 + u]); }
      *(us4*)&xbf[e] = o0; *(us4*)&xbf[e + 4] = o1;
    } else {
      *(us4*)&xbf[e]     = *(const us4*)&((const u16*)x)[e];
      *(us4*)&xbf[e + 4] = *(const us4*)&((const u16*)x)[e + 4];
    }
  } else {                                // ---- transposes ----
    __shared__ alignas(16) u16 tile[32][33];
    const void* in; u16* out; int C, bx, by;
    if (bid < 4096 + 3072) { const int t = bid - 4096; in = w_qkv; out = wqkvT; C = 3072; bx = t % 96; by = t / 96; }
    else                   { const int t = bid - 7168; in = w_out; out = woutT; C = 1024; bx = t % 32; by = t / 32; }
    const int R = 1024;
    const int tx = tid & 31, ty = tid >> 5;
    const int xg = bx * 32 + tx;
    const int y0 = by * 32;
    #pragma unroll
    for (int i = ty; i < 32; i += 8) {
      u16 v;
      if (isf) v = f2bf(((const float*)in)[(size_t)(y0 + i) * C + xg]);
      else     v = ((const u16*)in)[(size_t)(y0 + i) * C + xg];
      tile[i][tx] = v;
    }
    __syncthreads();
    const int ox  = y0 + tx;
    const int oy0 = bx * 32;
    #pragma unroll
    for (int i = ty; i < 32; i += 8)
      out[(size_t)(oy0 + i) * R + ox] = tile[tx][i];
  }
}

// ---------------- bf16 GEMM, C[M,N] = A[M,K(lda)] * Bt[N,K]^T ----------------
// BK=64 (16 K-tiles at K=1024 -> half the barrier drains of BK=32).
// LDS row = 128B (8 chunks of 16B). Slot (row, c) holds GLOBAL chunk c ^ (row&7):
// fragment b128 reads spread 64 lanes 8-per-chunk-column = minimum-time LDS access.
// Staging: 4 global_load_lds x 4KB per matrix; instr s covers rows s*32..s*32+31.
template<bool ADYN, bool CDYN>
__global__ __launch_bounds__(256, 4) void gemm_bt(
    const void* __restrict__ A, const u16* __restrict__ Bt,
    void* __restrict__ C, int N, int K, int lda, int ldc,
    const int* __restrict__ flag)
{
  __shared__ alignas(16) u16 As[128 * 64];   // 16 KB
  __shared__ alignas(16) u16 Bs[128 * 64];   // 16 KB

  const int isf  = ADYN ? *flag : 0;
  const int tid  = threadIdx.x;
  const int lane = tid & 63;
  const int w    = tid >> 6;
  const int wm   = (w >> 1) * 64;
  const int wn   = (w & 1) * 64;
  const int quad = lane >> 4;
  const int l16  = lane & 15;
  const int row0 = blockIdx.y * 128;
  const int col0 = blockIdx.x * 128;

  f4 acc[4][4] = {};

  // staging geometry: instr s -> row r = s*32 + tid/8, LDS chunk tid&7,
  // global chunk (tid&7)^(r&7); LDS byte dest = s*4096 + tid*16.
  size_t aoff[4]; const u16* bsrc[4]; int lofs[4];
  #pragma unroll
  for (int s = 0; s < 4; ++s) {
    const int r  = s * 32 + (tid >> 3);
    const int gc = (tid & 7) ^ (r & 7);
    aoff[s] = (size_t)(row0 + r) * lda + gc * 8;
    bsrc[s] = Bt + (size_t)(col0 + r) * K + gc * 8;
    lofs[s] = s * 4096 + tid * 16;
  }

  const bool af32 = ADYN && isf;

  for (int k0 = 0; k0 < K; k0 += 64) {
    if (af32) {
      // fp32 A fallback: register stage + convert (B still async)
      const float* Af = (const float*)A;
      bh8 a[4];
      #pragma unroll
      for (int s = 0; s < 4; ++s) {
        f4 u0 = *(const f4*)(Af + aoff[s] + k0);
        f4 u1 = *(const f4*)(Af + aoff[s] + k0 + 4);
        #pragma unroll
        for (int u = 0; u < 4; ++u) { a[s][u] = (short)f2bf(u0[u]); a[s][u + 4] = (short)f2bf(u1[u]); }
      }
      __syncthreads();
      #pragma unroll
      for (int s = 0; s < 4; ++s) {
        *(bh8*)((char*)As + lofs[s]) = a[s];
        async16(bsrc[s] + k0, (char*)Bs + lofs[s]);
      }
    } else {
      const u16* A16 = (const u16*)A;
      __syncthreads();               // prev-iter LDS readers done before overwrite
      #pragma unroll
      for (int s = 0; s < 4; ++s) {
        async16(A16 + aoff[s] + k0, (char*)As + lofs[s]);
        async16(bsrc[s] + k0,       (char*)Bs + lofs[s]);
      }
    }
    __builtin_amdgcn_s_waitcnt(0);   // drain DMA before barrier
    __syncthreads();

    #pragma unroll
    for (int ks = 0; ks < 2; ++ks) {
      bh8 af[4], bf[4];
      #pragma unroll
      for (int i = 0; i < 4; ++i) {
        const int row = wm + i * 16 + l16;
        const int lc  = (ks * 4 + quad) ^ (row & 7);
        af[i] = *(const bh8*)(As + row * 64 + lc * 8);
      }
      #pragma unroll
      for (int j = 0; j < 4; ++j) {
        const int row = wn + j * 16 + l16;
        const int lc  = (ks * 4 + quad) ^ (row & 7);
        bf[j] = *(const bh8*)(Bs + row * 64 + lc * 8);
      }
      #pragma unroll
      for (int i = 0; i < 4; ++i)
        #pragma unroll
        for (int j = 0; j < 4; ++j)
          acc[i][j] = __builtin_amdgcn_mfma_f32_16x16x32_bf16(af[i], bf[j], acc[i][j], 0, 0, 0);
    }
  }

  // C/D layout: col = lane&15, row = quad*4 + reg
  const bool cf32 = CDYN && (*flag);
  #pragma unroll
  for (int i = 0; i < 4; ++i) {
    #pragma unroll
    for (int j = 0; j < 4; ++j) {
      const int rb = row0 + wm + i * 16 + quad * 4;
      const int cc = col0 + wn + j * 16 + l16;
      #pragma unroll
      for (int r = 0; r < 4; ++r) {
        if (cf32) ((float*)C)[(size_t)(rb + r) * ldc + cc] = acc[i][j][r];
        else      ((u16*)C)[(size_t)(rb + r) * ldc + cc]   = f2bf(acc[i][j][r]);
      }
    }
  }
}

// ---------------- MFMA flash-style sliding-window attention (unchanged) --------------
__global__ __launch_bounds__(256) void attn_mfma(u16* __restrict__ qkv)
{
  __shared__ alignas(16) u16 Qs[64 * 72];
  __shared__ alignas(16) u16 Kt[64 * 72];
  __shared__ alignas(16) u16 Vt[64 * 72];   // (d,k): d*72 + ((k>>3)^(d>>3))*8 + (k&7)
  __shared__ alignas(16) u16 Ps[64 * 72];   // (q,k): q*72 + ((k>>3)^((q>>3)&1))*8 + (k&7)

  const int tid  = threadIdx.x;
  const int lane = tid & 63;
  const int w    = tid >> 6;
  const int quad = lane >> 4;
  const int l16  = lane & 15;
  const int qb = blockIdx.x, h = blockIdx.y, b = blockIdx.z;
  const int qs = qb * 64;

  const u16* base = qkv + (size_t)b * T_SEQ * 3072 + h * 64;

  const int c8  = (tid & 7) * 8;
  const int r0s = tid >> 3;
  #pragma unroll
  for (int r = r0s; r < 64; r += 32)
    *(bh8*)&Qs[r * 72 + c8] = *(const bh8*)&base[(size_t)(qs + r) * 3072 + c8];

  f4 Oc[4] = {};
  float mst[4] = {-1e30f, -1e30f, -1e30f, -1e30f};
  float lst[4] = {0.f, 0.f, 0.f, 0.f};

  const int tmin = (qb >= 4) ? 0 : (4 - qb);

  for (int t = tmin; t < 5; ++t) {
    const int kt0 = qs - 256 + t * 64;
    __syncthreads();

    #pragma unroll
    for (int r = r0s; r < 64; r += 32) {
      *(bh8*)&Kt[r * 72 + c8] =
          *(const bh8*)&base[(size_t)(kt0 + r) * 3072 + 1024 + c8];
      bh8 v = *(const bh8*)&base[(size_t)(kt0 + r) * 3072 + 2048 + c8];
      const int kc = r >> 3, ki = r & 7;
      #pragma unroll
      for (int u = 0; u < 8; ++u) {
        const int d = c8 + u;
        Vt[d * 72 + ((kc ^ (d >> 3)) << 3) + ki] = (u16)v[u];
      }
    }
    __syncthreads();

    const int qrow = (w * 16 + l16) * 72;
    bh8 qa0 = *(const bh8*)&Qs[qrow + quad * 8];
    bh8 qa1 = *(const bh8*)&Qs[qrow + 32 + quad * 8];
    f4 S[4];
    #pragma unroll
    for (int kb = 0; kb < 4; ++kb) {
      const int krow = (kb * 16 + l16) * 72;
      bh8 kf0 = *(const bh8*)&Kt[krow + quad * 8];
      bh8 kf1 = *(const bh8*)&Kt[krow + 32 + quad * 8];
      f4 s = {};
      s = __builtin_amdgcn_mfma_f32_16x16x32_bf16(qa0, kf0, s, 0, 0, 0);
      s = __builtin_amdgcn_mfma_f32_16x16x32_bf16(qa1, kf1, s, 0, 0, 0);
      S[kb] = s;
    }

    const int iq0 = qs + w * 16 + quad * 4;
    float tmax[4] = {-1e30f, -1e30f, -1e30f, -1e30f};
    #pragma unroll
    for (int kb = 0; kb < 4; ++kb) {
      const int j = kt0 + kb * 16 + l16;
      #pragma unroll
      for (int rr = 0; rr < 4; ++rr) {
        const int i = iq0 + rr;
        float s = S[kb][rr] * 0.125f;
        const bool ok = (j <= i) && (j > i - WIN);
        s = ok ? s : -1e30f;
        S[kb][rr] = s;
        tmax[rr] = fmaxf(tmax[rr], s);
      }
    }
    #pragma unroll
    for (int off = 1; off < 16; off <<= 1)
      #pragma unroll
      for (int rr = 0; rr < 4; ++rr)
        tmax[rr] = fmaxf(tmax[rr], __shfl_xor(tmax[rr], off));

    float alpha[4], rsum[4];
    #pragma unroll
    for (int rr = 0; rr < 4; ++rr) {
      const float mnew = fmaxf(mst[rr], tmax[rr]);
      alpha[rr] = __expf(mst[rr] - mnew);
      mst[rr] = mnew;
      rsum[rr] = 0.f;
    }

    const int swq = quad >> 1;
    #pragma unroll
    for (int kb = 0; kb < 4; ++kb) {
      const int kc = kb * 2 + (l16 >> 3);
      const int ki = l16 & 7;
      #pragma unroll
      for (int rr = 0; rr < 4; ++rr) {
        const float sv = S[kb][rr];
        const float p = (sv > -0.5e30f) ? __expf(sv - mst[rr]) : 0.f;
        rsum[rr] += p;
        const int q = w * 16 + quad * 4 + rr;
        Ps[q * 72 + ((kc ^ swq) << 3) + ki] = f2bf(p);
      }
    }
    #pragma unroll
    for (int off = 1; off < 16; off <<= 1)
      #pragma unroll
      for (int rr = 0; rr < 4; ++rr)
        rsum[rr] += __shfl_xor(rsum[rr], off);
    #pragma unroll
    for (int rr = 0; rr < 4; ++rr)
      lst[rr] = lst[rr] * alpha[rr] + rsum[rr];

    #pragma unroll
    for (int db = 0; db < 4; ++db)
      #pragma unroll
      for (int rr = 0; rr < 4; ++rr)
        Oc[db][rr] *= alpha[rr];

    {
      const int q = w * 16 + l16;
      const int sw = (q >> 3) & 1;
      bh8 pa0 = *(const bh8*)&Ps[q * 72 + (((0 + quad) ^ sw) << 3)];
      bh8 pa1 = *(const bh8*)&Ps[q * 72 + (((4 + quad) ^ sw) << 3)];
      #pragma unroll
      for (int db = 0; db < 4; ++db) {
        const int d = db * 16 + l16;
        const int dsw = d >> 3;
        bh8 vb0 = *(const bh8*)&Vt[d * 72 + (((0 + quad) ^ dsw) << 3)];
        bh8 vb1 = *(const bh8*)&Vt[d * 72 + (((4 + quad) ^ dsw) << 3)];
        Oc[db] = __builtin_amdgcn_mfma_f32_16x16x32_bf16(pa0, vb0, Oc[db], 0, 0, 0);
        Oc[db] = __builtin_amdgcn_mfma_f32_16x16x32_bf16(pa1, vb1, Oc[db], 0, 0, 0);
      }
    }
  }

  u16* obase = (u16*)base;
  #pragma unroll
  for (int rr = 0; rr < 4; ++rr) {
    const int i = qs + w * 16 + quad * 4 + rr;
    const float inv = 1.f / lst[rr];
    #pragma unroll
    for (int db = 0; db < 4; ++db)
      obase[(size_t)i * 3072 + db * 16 + l16] = f2bf(Oc[db][rr] * inv);
  }
}

// ---------------- launcher ----------------
extern "C" void kernel_launch(void* const* d_in, const int* in_sizes, int n_in,
                              void* d_out, int out_size, void* d_ws, size_t ws_size,
                              hipStream_t stream) {
  const void* x     = d_in[0];   // [8192, 1024]  fp32 or bf16 (auto-detected)
  const void* w_qkv = d_in[1];   // [1024, 3072]
  const void* w_out = d_in[2];   // [1024, 1024]

  const size_t SZ_QKV  = (size_t)8192 * 3072 * 2;
  const size_t SZ_XBF  = (size_t)8192 * 1024 * 2;
  const size_t SZ_WQ   = (size_t)3072 * 1024 * 2;
  const size_t SZ_WO   = (size_t)1024 * 1024 * 2;

  char* p = (char*)d_ws;
  u16* qkv   = (u16*)p; p += SZ_QKV;
  u16* wqkvT = (u16*)p; p += SZ_WQ;
  u16* woutT = (u16*)p; p += SZ_WO;
  int* flag  = (int*)p; p += 16;
  u16* xbf   = (u16*)p;
  const bool have_x = ws_size >= (SZ_QKV + SZ_WQ + SZ_WO + 16 + SZ_XBF);

  detect_dtype<<<1, 64, 0, stream>>>(x, flag);

  prep<<<dim3(8192), 256, 0, stream>>>(x, w_qkv, w_out, xbf, wqkvT, woutT,
                                       flag, have_x ? 1 : 0);

  if (have_x) {
    gemm_bt<false, false><<<dim3(24, 64), 256, 0, stream>>>(
        xbf, wqkvT, qkv, 3072, 1024, 1024, 3072, flag);
  } else {
    gemm_bt<true, false><<<dim3(24, 64), 256, 0, stream>>>(
        x, wqkvT, qkv, 3072, 1024, 1024, 3072, flag);
  }

  attn_mfma<<<dim3(32, NHEADS, 4), 256, 0, stream>>>(qkv);

  gemm_bt<false, true><<<dim3(8, 64), 256, 0, stream>>>(
      qkv, woutT, d_out, 1024, 1024, 3072, 1024, flag);
}

// Round 7
// 225.331 us; speedup vs baseline: 1.1907x; 1.0619x over previous
//
#include <hip/hip_runtime.h>

typedef unsigned short u16;
typedef __attribute__((ext_vector_type(8))) short bh8;     // 8 bf16 MFMA A/B frag
typedef __attribute__((ext_vector_type(4))) float f4;      // MFMA C/D frag / float4
typedef __attribute__((ext_vector_type(4))) unsigned short us4;

#define T_SEQ 2048
#define NHEADS 16
#define DHEAD 64
#define WIN 256

__device__ __forceinline__ float bf2f(u16 u) {
  union { unsigned int i; float f; } v; v.i = ((unsigned int)u) << 16; return v.f;
}
__device__ __forceinline__ u16 f2bf(float f) {
  unsigned int u = __float_as_uint(f);
  u = u + 0x7fffu + ((u >> 16) & 1u);   // RNE
  return (u16)(u >> 16);
}
__device__ __forceinline__ void async16(const void* g, void* l) {
  void* gv = const_cast<void*>(g);
  __builtin_amdgcn_global_load_lds(
      (__attribute__((address_space(1))) void*)gv,
      (__attribute__((address_space(3))) void*)l, 16, 0, 0);
}

// ---------------- dtype detect (parallel): 1 if plausibly fp32, else 0 ----------
__global__ void detect_dtype(const void* x, int* flag) {
  __shared__ int bad;
  if (threadIdx.x == 0) bad = 0;
  __syncthreads();
  const float v = ((const float*)x)[threadIdx.x];    // 256 parallel probes
  const float a = fabsf(v);
  const int lane_bad = (!(a < 64.f)) || (!(v == 0.f || a > 1e-30f));
  if (__any(lane_bad)) { if ((threadIdx.x & 63) == 0) bad = 1; }
  __syncthreads();
  if (threadIdx.x == 0) *flag = bad ? 0 : 1;
}

// ---------------- fused prep: xconv + transpose(w_qkv) + transpose(w_out) ------------
__global__ __launch_bounds__(256) void prep(
    const void* __restrict__ x, const void* __restrict__ w_qkv,
    const void* __restrict__ w_out, u16* __restrict__ xbf,
    u16* __restrict__ wqkvT, u16* __restrict__ woutT,
    const int* __restrict__ flag, int have_x)
{
  const int bid = blockIdx.x;
  const int tid = threadIdx.x;
  const int isf = *flag;

  if (bid < 4096) {                       // ---- xconv ----
    if (!have_x) return;
    const size_t e = ((size_t)bid * 256 + tid) * 8;
    if (isf) {
      const float* f = (const float*)x;
      us4 o0, o1;
      #pragma unroll
      for (int u = 0; u < 4; ++u) { o0[u] = f2bf(f[e + u]); o1[u] = f2bf(f[e + 4 + u]); }
      *(us4*)&xbf[e] = o0; *(us4*)&xbf[e + 4] = o1;
    } else {
      *(us4*)&xbf[e]     = *(const us4*)&((const u16*)x)[e];
      *(us4*)&xbf[e + 4] = *(const us4*)&((const u16*)x)[e + 4];
    }
  } else {                                // ---- transposes ----
    __shared__ alignas(16) u16 tile[32][33];
    const void* in; u16* out; int C, bx, by;
    if (bid < 4096 + 3072) { const int t = bid - 4096; in = w_qkv; out = wqkvT; C = 3072; bx = t % 96; by = t / 96; }
    else                   { const int t = bid - 7168; in = w_out; out = woutT; C = 1024; bx = t % 32; by = t / 32; }
    const int R = 1024;
    const int tx = tid & 31, ty = tid >> 5;
    const int xg = bx * 32 + tx;
    const int y0 = by * 32;
    #pragma unroll
    for (int i = ty; i < 32; i += 8) {
      u16 v;
      if (isf) v = f2bf(((const float*)in)[(size_t)(y0 + i) * C + xg]);
      else     v = ((const u16*)in)[(size_t)(y0 + i) * C + xg];
      tile[i][tx] = v;
    }
    __syncthreads();
    const int ox  = y0 + tx;
    const int oy0 = bx * 32;
    #pragma unroll
    for (int i = ty; i < 32; i += 8)
      out[(size_t)(oy0 + i) * R + ox] = tile[tx][i];
  }
}

// ---------------- bf16 GEMM, C[M,N] = A[M,K(lda)] * Bt[N,K]^T ----------------
// BK=64; 128 x BN tile (BN=128 or 64). LDS row = 128B (8 chunks of 16B);
// slot (row,c) holds GLOBAL chunk c ^ (row&7) -> conflict-free b128 frag reads.
template<bool ADYN, bool CDYN, int BN>
__global__ __launch_bounds__(256, 4) void gemm_bt(
    const void* __restrict__ A, const u16* __restrict__ Bt,
    void* __restrict__ C, int N, int K, int lda, int ldc,
    const int* __restrict__ flag)
{
  constexpr int NJ = BN / 32;            // B frags per wave (4 or 2)
  constexpr int SB = BN / 32;            // B staging instrs (4 or 2)
  __shared__ alignas(16) u16 As[128 * 64];
  __shared__ alignas(16) u16 Bs[BN * 64];

  const int isf  = ADYN ? *flag : 0;
  const int tid  = threadIdx.x;
  const int lane = tid & 63;
  const int w    = tid >> 6;
  const int wm   = (w >> 1) * 64;
  const int wn   = (w & 1) * (BN / 2);
  const int quad = lane >> 4;
  const int l16  = lane & 15;
  const int row0 = blockIdx.y * 128;
  const int col0 = blockIdx.x * BN;

  f4 acc[4][NJ] = {};

  size_t aoff[4]; const u16* bsrc[SB]; int lofs[4];
  #pragma unroll
  for (int s = 0; s < 4; ++s) {
    const int r  = s * 32 + (tid >> 3);
    const int gc = (tid & 7) ^ (r & 7);
    aoff[s] = (size_t)(row0 + r) * lda + gc * 8;
    lofs[s] = s * 4096 + tid * 16;
  }
  #pragma unroll
  for (int s = 0; s < SB; ++s) {
    const int r  = s * 32 + (tid >> 3);
    const int gc = (tid & 7) ^ (r & 7);
    bsrc[s] = Bt + (size_t)(col0 + r) * K + gc * 8;
  }

  const bool af32 = ADYN && isf;

  for (int k0 = 0; k0 < K; k0 += 64) {
    if (af32) {
      const float* Af = (const float*)A;
      bh8 a[4];
      #pragma unroll
      for (int s = 0; s < 4; ++s) {
        f4 u0 = *(const f4*)(Af + aoff[s] + k0);
        f4 u1 = *(const f4*)(Af + aoff[s] + k0 + 4);
        #pragma unroll
        for (int u = 0; u < 4; ++u) { a[s][u] = (short)f2bf(u0[u]); a[s][u + 4] = (short)f2bf(u1[u]); }
      }
      __syncthreads();
      #pragma unroll
      for (int s = 0; s < 4; ++s) *(bh8*)((char*)As + lofs[s]) = a[s];
      #pragma unroll
      for (int s = 0; s < SB; ++s) async16(bsrc[s] + k0, (char*)Bs + lofs[s]);
    } else {
      const u16* A16 = (const u16*)A;
      __syncthreads();
      #pragma unroll
      for (int s = 0; s < 4; ++s) async16(A16 + aoff[s] + k0, (char*)As + lofs[s]);
      #pragma unroll
      for (int s = 0; s < SB; ++s) async16(bsrc[s] + k0, (char*)Bs + lofs[s]);
    }
    __builtin_amdgcn_s_waitcnt(0);
    __syncthreads();

    #pragma unroll
    for (int ks = 0; ks < 2; ++ks) {
      bh8 af[4], bf[NJ];
      #pragma unroll
      for (int i = 0; i < 4; ++i) {
        const int row = wm + i * 16 + l16;
        const int lc  = (ks * 4 + quad) ^ (row & 7);
        af[i] = *(const bh8*)(As + row * 64 + lc * 8);
      }
      #pragma unroll
      for (int j = 0; j < NJ; ++j) {
        const int row = wn + j * 16 + l16;
        const int lc  = (ks * 4 + quad) ^ (row & 7);
        bf[j] = *(const bh8*)(Bs + row * 64 + lc * 8);
      }
      #pragma unroll
      for (int i = 0; i < 4; ++i)
        #pragma unroll
        for (int j = 0; j < NJ; ++j)
          acc[i][j] = __builtin_amdgcn_mfma_f32_16x16x32_bf16(af[i], bf[j], acc[i][j], 0, 0, 0);
    }
  }

  const bool cf32 = CDYN && (*flag);
  #pragma unroll
  for (int i = 0; i < 4; ++i) {
    #pragma unroll
    for (int j = 0; j < NJ; ++j) {
      const int rb = row0 + wm + i * 16 + quad * 4;
      const int cc = col0 + wn + j * 16 + l16;
      #pragma unroll
      for (int r = 0; r < 4; ++r) {
        if (cf32) ((float*)C)[(size_t)(rb + r) * ldc + cc] = acc[i][j][r];
        else      ((u16*)C)[(size_t)(rb + r) * ldc + cc]   = f2bf(acc[i][j][r]);
      }
    }
  }
}

// ---------------- MFMA flash-style sliding-window attention ----------------
// Q fragments live in registers (loaded once, coalesced); LDS = Kt+Vt+Ps = 27.6 KB
// -> 5 blocks/CU. Output in-place into the q-channel.
__global__ __launch_bounds__(256) void attn_mfma(u16* __restrict__ qkv)
{
  __shared__ alignas(16) u16 Kt[64 * 72];
  __shared__ alignas(16) u16 Vt[64 * 72];   // (d,k): d*72 + ((k>>3)^(d>>3))*8 + (k&7)
  __shared__ alignas(16) u16 Ps[64 * 72];   // (q,k): q*72 + ((k>>3)^((q>>3)&1))*8 + (k&7)

  const int tid  = threadIdx.x;
  const int lane = tid & 63;
  const int w    = tid >> 6;
  const int quad = lane >> 4;
  const int l16  = lane & 15;
  const int qb = blockIdx.x, h = blockIdx.y, b = blockIdx.z;
  const int qs = qb * 64;

  const u16* base = qkv + (size_t)b * T_SEQ * 3072 + h * 64;

  // Q fragments straight to registers: row = qs + w*16 + l16, cols quad*8 / 32+quad*8
  const size_t qrowg = (size_t)(qs + w * 16 + l16) * 3072;
  bh8 qa0 = *(const bh8*)&base[qrowg + quad * 8];
  bh8 qa1 = *(const bh8*)&base[qrowg + 32 + quad * 8];

  f4 Oc[4] = {};
  float mst[4] = {-1e30f, -1e30f, -1e30f, -1e30f};
  float lst[4] = {0.f, 0.f, 0.f, 0.f};

  const int tmin = (qb >= 4) ? 0 : (4 - qb);
  const int c8  = (tid & 7) * 8;
  const int r0s = tid >> 3;

  for (int t = tmin; t < 5; ++t) {
    const int kt0 = qs - 256 + t * 64;
    __syncthreads();

    #pragma unroll
    for (int r = r0s; r < 64; r += 32) {
      *(bh8*)&Kt[r * 72 + c8] =
          *(const bh8*)&base[(size_t)(kt0 + r) * 3072 + 1024 + c8];
      bh8 v = *(const bh8*)&base[(size_t)(kt0 + r) * 3072 + 2048 + c8];
      const int kc = r >> 3, ki = r & 7;
      #pragma unroll
      for (int u = 0; u < 8; ++u) {
        const int d = c8 + u;
        Vt[d * 72 + ((kc ^ (d >> 3)) << 3) + ki] = (u16)v[u];
      }
    }
    __syncthreads();

    f4 S[4];
    #pragma unroll
    for (int kb = 0; kb < 4; ++kb) {
      const int krow = (kb * 16 + l16) * 72;
      bh8 kf0 = *(const bh8*)&Kt[krow + quad * 8];
      bh8 kf1 = *(const bh8*)&Kt[krow + 32 + quad * 8];
      f4 s = {};
      s = __builtin_amdgcn_mfma_f32_16x16x32_bf16(qa0, kf0, s, 0, 0, 0);
      s = __builtin_amdgcn_mfma_f32_16x16x32_bf16(qa1, kf1, s, 0, 0, 0);
      S[kb] = s;
    }

    const int iq0 = qs + w * 16 + quad * 4;
    float tmax[4] = {-1e30f, -1e30f, -1e30f, -1e30f};
    #pragma unroll
    for (int kb = 0; kb < 4; ++kb) {
      const int j = kt0 + kb * 16 + l16;
      #pragma unroll
      for (int rr = 0; rr < 4; ++rr) {
        const int i = iq0 + rr;
        float s = S[kb][rr] * 0.125f;
        const bool ok = (j <= i) && (j > i - WIN);
        s = ok ? s : -1e30f;
        S[kb][rr] = s;
        tmax[rr] = fmaxf(tmax[rr], s);
      }
    }
    #pragma unroll
    for (int off = 1; off < 16; off <<= 1)
      #pragma unroll
      for (int rr = 0; rr < 4; ++rr)
        tmax[rr] = fmaxf(tmax[rr], __shfl_xor(tmax[rr], off));

    float alpha[4], rsum[4];
    #pragma unroll
    for (int rr = 0; rr < 4; ++rr) {
      const float mnew = fmaxf(mst[rr], tmax[rr]);
      alpha[rr] = __expf(mst[rr] - mnew);
      mst[rr] = mnew;
      rsum[rr] = 0.f;
    }

    const int swq = quad >> 1;
    #pragma unroll
    for (int kb = 0; kb < 4; ++kb) {
      const int kc = kb * 2 + (l16 >> 3);
      const int ki = l16 & 7;
      #pragma unroll
      for (int rr = 0; rr < 4; ++rr) {
        const float sv = S[kb][rr];
        const float p = (sv > -0.5e30f) ? __expf(sv - mst[rr]) : 0.f;
        rsum[rr] += p;
        const int q = w * 16 + quad * 4 + rr;
        Ps[q * 72 + ((kc ^ swq) << 3) + ki] = f2bf(p);
      }
    }
    #pragma unroll
    for (int off = 1; off < 16; off <<= 1)
      #pragma unroll
      for (int rr = 0; rr < 4; ++rr)
        rsum[rr] += __shfl_xor(rsum[rr], off);
    #pragma unroll
    for (int rr = 0; rr < 4; ++rr)
      lst[rr] = lst[rr] * alpha[rr] + rsum[rr];

    #pragma unroll
    for (int db = 0; db < 4; ++db)
      #pragma unroll
      for (int rr = 0; rr < 4; ++rr)
        Oc[db][rr] *= alpha[rr];

    {
      const int q = w * 16 + l16;
      const int sw = (q >> 3) & 1;
      bh8 pa0 = *(const bh8*)&Ps[q * 72 + (((0 + quad) ^ sw) << 3)];
      bh8 pa1 = *(const bh8*)&Ps[q * 72 + (((4 + quad) ^ sw) << 3)];
      #pragma unroll
      for (int db = 0; db < 4; ++db) {
        const int d = db * 16 + l16;
        const int dsw = d >> 3;
        bh8 vb0 = *(const bh8*)&Vt[d * 72 + (((0 + quad) ^ dsw) << 3)];
        bh8 vb1 = *(const bh8*)&Vt[d * 72 + (((4 + quad) ^ dsw) << 3)];
        Oc[db] = __builtin_amdgcn_mfma_f32_16x16x32_bf16(pa0, vb0, Oc[db], 0, 0, 0);
        Oc[db] = __builtin_amdgcn_mfma_f32_16x16x32_bf16(pa1, vb1, Oc[db], 0, 0, 0);
      }
    }
  }

  u16* obase = (u16*)base;
  #pragma unroll
  for (int rr = 0; rr < 4; ++rr) {
    const int i = qs + w * 16 + quad * 4 + rr;
    const float inv = 1.f / lst[rr];
    #pragma unroll
    for (int db = 0; db < 4; ++db)
      obase[(size_t)i * 3072 + db * 16 + l16] = f2bf(Oc[db][rr] * inv);
  }
}

// ---------------- launcher ----------------
extern "C" void kernel_launch(void* const* d_in, const int* in_sizes, int n_in,
                              void* d_out, int out_size, void* d_ws, size_t ws_size,
                              hipStream_t stream) {
  const void* x     = d_in[0];   // [8192, 1024]  fp32 or bf16 (auto-detected)
  const void* w_qkv = d_in[1];   // [1024, 3072]
  const void* w_out = d_in[2];   // [1024, 1024]

  const size_t SZ_QKV  = (size_t)8192 * 3072 * 2;
  const size_t SZ_XBF  = (size_t)8192 * 1024 * 2;
  const size_t SZ_WQ   = (size_t)3072 * 1024 * 2;
  const size_t SZ_WO   = (size_t)1024 * 1024 * 2;

  char* p = (char*)d_ws;
  u16* qkv   = (u16*)p; p += SZ_QKV;
  u16* wqkvT = (u16*)p; p += SZ_WQ;
  u16* woutT = (u16*)p; p += SZ_WO;
  int* flag  = (int*)p; p += 16;
  u16* xbf   = (u16*)p;
  const bool have_x = ws_size >= (SZ_QKV + SZ_WQ + SZ_WO + 16 + SZ_XBF);

  detect_dtype<<<1, 256, 0, stream>>>(x, flag);

  prep<<<dim3(8192), 256, 0, stream>>>(x, w_qkv, w_out, xbf, wqkvT, woutT,
                                       flag, have_x ? 1 : 0);

  if (have_x) {
    gemm_bt<false, false, 128><<<dim3(24, 64), 256, 0, stream>>>(
        xbf, wqkvT, qkv, 3072, 1024, 1024, 3072, flag);
  } else {
    gemm_bt<true, false, 128><<<dim3(24, 64), 256, 0, stream>>>(
        x, wqkvT, qkv, 3072, 1024, 1024, 3072, flag);
  }

  attn_mfma<<<dim3(32, NHEADS, 4), 256, 0, stream>>>(qkv);

  // gemm2: 128x64 tiles -> 1024 blocks (4/CU residency)
  gemm_bt<false, true, 64><<<dim3(16, 64), 256, 0, stream>>>(
      qkv, woutT, d_out, 1024, 1024, 3072, 1024, flag);
}

// Round 8
// 217.405 us; speedup vs baseline: 1.2341x; 1.0365x over previous
//
#include <hip/hip_runtime.h>

typedef unsigned short u16;
typedef __attribute__((ext_vector_type(8))) short bh8;     // 8 bf16 MFMA A/B frag
typedef __attribute__((ext_vector_type(4))) float f4;      // MFMA C/D frag / float4
typedef __attribute__((ext_vector_type(4))) unsigned short us4;

#define T_SEQ 2048
#define NHEADS 16
#define DHEAD 64
#define WIN 256

__device__ __forceinline__ float bf2f(u16 u) {
  union { unsigned int i; float f; } v; v.i = ((unsigned int)u) << 16; return v.f;
}
__device__ __forceinline__ u16 f2bf(float f) {
  unsigned int u = __float_as_uint(f);
  u = u + 0x7fffu + ((u >> 16) & 1u);   // RNE
  return (u16)(u >> 16);
}
__device__ __forceinline__ void async16(const void* g, void* l) {
  void* gv = const_cast<void*>(g);
  __builtin_amdgcn_global_load_lds(
      (__attribute__((address_space(1))) void*)gv,
      (__attribute__((address_space(3))) void*)l, 16, 0, 0);
}

// Inline dtype probe: 1 if x[0..255] plausible as fp32. Wave-uniform (ballot),
// deterministic across all blocks/kernels -> no separate detect kernel needed.
__device__ __forceinline__ int is_f32_probe(const void* x) {
  const float* xf = (const float*)x;
  const int lane = threadIdx.x & 63;
  int bad = 0;
  #pragma unroll
  for (int u = 0; u < 4; ++u) {
    const float v = xf[lane * 4 + u];
    const float a = fabsf(v);
    bad |= (!(a < 64.f)) || (!(v == 0.f || a > 1e-30f));
  }
  return __any(bad) ? 0 : 1;
}

// ---------------- fused prep: xconv + transpose(w_qkv) + transpose(w_out) ------------
__global__ __launch_bounds__(256) void prep(
    const void* __restrict__ x, const void* __restrict__ w_qkv,
    const void* __restrict__ w_out, u16* __restrict__ xbf,
    u16* __restrict__ wqkvT, u16* __restrict__ woutT, int have_x)
{
  const int bid = blockIdx.x;
  const int tid = threadIdx.x;
  const int isf = is_f32_probe(x);

  if (bid < 4096) {                       // ---- xconv ----
    if (!have_x) return;
    const size_t e = ((size_t)bid * 256 + tid) * 8;
    if (isf) {
      const float* f = (const float*)x;
      us4 o0, o1;
      #pragma unroll
      for (int u = 0; u < 4; ++u) { o0[u] = f2bf(f[e + u]); o1[u] = f2bf(f[e + 4 + u]); }
      *(us4*)&xbf[e] = o0; *(us4*)&xbf[e + 4] = o1;
    } else {
      *(us4*)&xbf[e]     = *(const us4*)&((const u16*)x)[e];
      *(us4*)&xbf[e + 4] = *(const us4*)&((const u16*)x)[e + 4];
    }
  } else {                                // ---- transposes ----
    __shared__ alignas(16) u16 tile[32][33];
    const void* in; u16* out; int C, bx, by;
    if (bid < 4096 + 3072) { const int t = bid - 4096; in = w_qkv; out = wqkvT; C = 3072; bx = t % 96; by = t / 96; }
    else                   { const int t = bid - 7168; in = w_out; out = woutT; C = 1024; bx = t % 32; by = t / 32; }
    const int R = 1024;
    const int tx = tid & 31, ty = tid >> 5;
    const int xg = bx * 32 + tx;
    const int y0 = by * 32;
    #pragma unroll
    for (int i = ty; i < 32; i += 8) {
      u16 v;
      if (isf) v = f2bf(((const float*)in)[(size_t)(y0 + i) * C + xg]);
      else     v = ((const u16*)in)[(size_t)(y0 + i) * C + xg];
      tile[i][tx] = v;
    }
    __syncthreads();
    const int ox  = y0 + tx;
    const int oy0 = bx * 32;
    #pragma unroll
    for (int i = ty; i < 32; i += 8)
      out[(size_t)(oy0 + i) * R + ox] = tile[tx][i];
  }
}

// ---------------- bf16 GEMM, C[M,N] = A[M,K(lda)] * Bt[N,K]^T ----------------
// BK=64; 128x128 tile. LDS row = 128B (8 chunks of 16B); slot (row,c) holds
// GLOBAL chunk c ^ (row&7) -> conflict-free b128 frag reads.
template<bool ADYN, bool CDYN>
__global__ __launch_bounds__(256, 4) void gemm_bt(
    const void* __restrict__ A, const u16* __restrict__ Bt,
    void* __restrict__ C, int N, int K, int lda, int ldc,
    const void* __restrict__ xprobe)
{
  __shared__ alignas(16) u16 As[128 * 64];
  __shared__ alignas(16) u16 Bs[128 * 64];

  const int isf  = (ADYN || CDYN) ? is_f32_probe(xprobe) : 0;
  const int tid  = threadIdx.x;
  const int lane = tid & 63;
  const int w    = tid >> 6;
  const int wm   = (w >> 1) * 64;
  const int wn   = (w & 1) * 64;
  const int quad = lane >> 4;
  const int l16  = lane & 15;
  const int row0 = blockIdx.y * 128;
  const int col0 = blockIdx.x * 128;

  f4 acc[4][4] = {};

  size_t aoff[4]; const u16* bsrc[4]; int lofs[4];
  #pragma unroll
  for (int s = 0; s < 4; ++s) {
    const int r  = s * 32 + (tid >> 3);
    const int gc = (tid & 7) ^ (r & 7);
    aoff[s] = (size_t)(row0 + r) * lda + gc * 8;
    bsrc[s] = Bt + (size_t)(col0 + r) * K + gc * 8;
    lofs[s] = s * 4096 + tid * 16;
  }

  const bool af32 = ADYN && isf;

  for (int k0 = 0; k0 < K; k0 += 64) {
    if (af32) {
      const float* Af = (const float*)A;
      bh8 a[4];
      #pragma unroll
      for (int s = 0; s < 4; ++s) {
        f4 u0 = *(const f4*)(Af + aoff[s] + k0);
        f4 u1 = *(const f4*)(Af + aoff[s] + k0 + 4);
        #pragma unroll
        for (int u = 0; u < 4; ++u) { a[s][u] = (short)f2bf(u0[u]); a[s][u + 4] = (short)f2bf(u1[u]); }
      }
      __syncthreads();
      #pragma unroll
      for (int s = 0; s < 4; ++s) {
        *(bh8*)((char*)As + lofs[s]) = a[s];
        async16(bsrc[s] + k0, (char*)Bs + lofs[s]);
      }
    } else {
      const u16* A16 = (const u16*)A;
      __syncthreads();
      #pragma unroll
      for (int s = 0; s < 4; ++s) {
        async16(A16 + aoff[s] + k0, (char*)As + lofs[s]);
        async16(bsrc[s] + k0,       (char*)Bs + lofs[s]);
      }
    }
    __builtin_amdgcn_s_waitcnt(0);
    __syncthreads();

    #pragma unroll
    for (int ks = 0; ks < 2; ++ks) {
      bh8 af[4], bf[4];
      #pragma unroll
      for (int i = 0; i < 4; ++i) {
        const int row = wm + i * 16 + l16;
        const int lc  = (ks * 4 + quad) ^ (row & 7);
        af[i] = *(const bh8*)(As + row * 64 + lc * 8);
      }
      #pragma unroll
      for (int j = 0; j < 4; ++j) {
        const int row = wn + j * 16 + l16;
        const int lc  = (ks * 4 + quad) ^ (row & 7);
        bf[j] = *(const bh8*)(Bs + row * 64 + lc * 8);
      }
      #pragma unroll
      for (int i = 0; i < 4; ++i)
        #pragma unroll
        for (int j = 0; j < 4; ++j)
          acc[i][j] = __builtin_amdgcn_mfma_f32_16x16x32_bf16(af[i], bf[j], acc[i][j], 0, 0, 0);
    }
  }

  const bool cf32 = CDYN && isf;
  #pragma unroll
  for (int i = 0; i < 4; ++i) {
    #pragma unroll
    for (int j = 0; j < 4; ++j) {
      const int rb = row0 + wm + i * 16 + quad * 4;
      const int cc = col0 + wn + j * 16 + l16;
      #pragma unroll
      for (int r = 0; r < 4; ++r) {
        if (cf32) ((float*)C)[(size_t)(rb + r) * ldc + cc] = acc[i][j][r];
        else      ((u16*)C)[(size_t)(rb + r) * ldc + cc]   = f2bf(acc[i][j][r]);
      }
    }
  }
}

// ---------------- MFMA flash-style sliding-window attention ----------------
// Q frags in registers; LDS = Kt+Vt+Ps = 27.6 KB -> 5 blocks/CU.
// Output -> att matrix [B*T, ldo] at column h*64 (ldo=1024 compact, or
// ldo=3072 with att=qkv for the in-place q-channel fallback).
__global__ __launch_bounds__(256) void attn_mfma(const u16* __restrict__ qkv,
                                                 u16* __restrict__ att, int ldo)
{
  __shared__ alignas(16) u16 Kt[64 * 72];
  __shared__ alignas(16) u16 Vt[64 * 72];   // (d,k): d*72 + ((k>>3)^(d>>3))*8 + (k&7)
  __shared__ alignas(16) u16 Ps[64 * 72];   // (q,k): q*72 + ((k>>3)^((q>>3)&1))*8 + (k&7)

  const int tid  = threadIdx.x;
  const int lane = tid & 63;
  const int w    = tid >> 6;
  const int quad = lane >> 4;
  const int l16  = lane & 15;
  const int qb = blockIdx.x, h = blockIdx.y, b = blockIdx.z;
  const int qs = qb * 64;

  const u16* base = qkv + (size_t)b * T_SEQ * 3072 + h * 64;

  const size_t qrowg = (size_t)(qs + w * 16 + l16) * 3072;
  bh8 qa0 = *(const bh8*)&base[qrowg + quad * 8];
  bh8 qa1 = *(const bh8*)&base[qrowg + 32 + quad * 8];

  f4 Oc[4] = {};
  float mst[4] = {-1e30f, -1e30f, -1e30f, -1e30f};
  float lst[4] = {0.f, 0.f, 0.f, 0.f};

  const int tmin = (qb >= 4) ? 0 : (4 - qb);
  const int c8  = (tid & 7) * 8;
  const int r0s = tid >> 3;

  for (int t = tmin; t < 5; ++t) {
    const int kt0 = qs - 256 + t * 64;
    __syncthreads();

    #pragma unroll
    for (int r = r0s; r < 64; r += 32) {
      *(bh8*)&Kt[r * 72 + c8] =
          *(const bh8*)&base[(size_t)(kt0 + r) * 3072 + 1024 + c8];
      bh8 v = *(const bh8*)&base[(size_t)(kt0 + r) * 3072 + 2048 + c8];
      const int kc = r >> 3, ki = r & 7;
      #pragma unroll
      for (int u = 0; u < 8; ++u) {
        const int d = c8 + u;
        Vt[d * 72 + ((kc ^ (d >> 3)) << 3) + ki] = (u16)v[u];
      }
    }
    __syncthreads();

    f4 S[4];
    #pragma unroll
    for (int kb = 0; kb < 4; ++kb) {
      const int krow = (kb * 16 + l16) * 72;
      bh8 kf0 = *(const bh8*)&Kt[krow + quad * 8];
      bh8 kf1 = *(const bh8*)&Kt[krow + 32 + quad * 8];
      f4 s = {};
      s = __builtin_amdgcn_mfma_f32_16x16x32_bf16(qa0, kf0, s, 0, 0, 0);
      s = __builtin_amdgcn_mfma_f32_16x16x32_bf16(qa1, kf1, s, 0, 0, 0);
      S[kb] = s;
    }

    const int iq0 = qs + w * 16 + quad * 4;
    float tmax[4] = {-1e30f, -1e30f, -1e30f, -1e30f};
    #pragma unroll
    for (int kb = 0; kb < 4; ++kb) {
      const int j = kt0 + kb * 16 + l16;
      #pragma unroll
      for (int rr = 0; rr < 4; ++rr) {
        const int i = iq0 + rr;
        float s = S[kb][rr] * 0.125f;
        const bool ok = (j <= i) && (j > i - WIN);
        s = ok ? s : -1e30f;
        S[kb][rr] = s;
        tmax[rr] = fmaxf(tmax[rr], s);
      }
    }
    #pragma unroll
    for (int off = 1; off < 16; off <<= 1)
      #pragma unroll
      for (int rr = 0; rr < 4; ++rr)
        tmax[rr] = fmaxf(tmax[rr], __shfl_xor(tmax[rr], off));

    float alpha[4], rsum[4];
    #pragma unroll
    for (int rr = 0; rr < 4; ++rr) {
      const float mnew = fmaxf(mst[rr], tmax[rr]);
      alpha[rr] = __expf(mst[rr] - mnew);
      mst[rr] = mnew;
      rsum[rr] = 0.f;
    }

    const int swq = quad >> 1;
    #pragma unroll
    for (int kb = 0; kb < 4; ++kb) {
      const int kc = kb * 2 + (l16 >> 3);
      const int ki = l16 & 7;
      #pragma unroll
      for (int rr = 0; rr < 4; ++rr) {
        const float sv = S[kb][rr];
        const float p = (sv > -0.5e30f) ? __expf(sv - mst[rr]) : 0.f;
        rsum[rr] += p;
        const int q = w * 16 + quad * 4 + rr;
        Ps[q * 72 + ((kc ^ swq) << 3) + ki] = f2bf(p);
      }
    }
    #pragma unroll
    for (int off = 1; off < 16; off <<= 1)
      #pragma unroll
      for (int rr = 0; rr < 4; ++rr)
        rsum[rr] += __shfl_xor(rsum[rr], off);
    #pragma unroll
    for (int rr = 0; rr < 4; ++rr)
      lst[rr] = lst[rr] * alpha[rr] + rsum[rr];

    #pragma unroll
    for (int db = 0; db < 4; ++db)
      #pragma unroll
      for (int rr = 0; rr < 4; ++rr)
        Oc[db][rr] *= alpha[rr];

    {
      const int q = w * 16 + l16;
      const int sw = (q >> 3) & 1;
      bh8 pa0 = *(const bh8*)&Ps[q * 72 + (((0 + quad) ^ sw) << 3)];
      bh8 pa1 = *(const bh8*)&Ps[q * 72 + (((4 + quad) ^ sw) << 3)];
      #pragma unroll
      for (int db = 0; db < 4; ++db) {
        const int d = db * 16 + l16;
        const int dsw = d >> 3;
        bh8 vb0 = *(const bh8*)&Vt[d * 72 + (((0 + quad) ^ dsw) << 3)];
        bh8 vb1 = *(const bh8*)&Vt[d * 72 + (((4 + quad) ^ dsw) << 3)];
        Oc[db] = __builtin_amdgcn_mfma_f32_16x16x32_bf16(pa0, vb0, Oc[db], 0, 0, 0);
        Oc[db] = __builtin_amdgcn_mfma_f32_16x16x32_bf16(pa1, vb1, Oc[db], 0, 0, 0);
      }
    }
  }

  u16* obase = att + (size_t)b * T_SEQ * ldo + h * 64;
  #pragma unroll
  for (int rr = 0; rr < 4; ++rr) {
    const int i = qs + w * 16 + quad * 4 + rr;
    const float inv = 1.f / lst[rr];
    #pragma unroll
    for (int db = 0; db < 4; ++db)
      obase[(size_t)i * ldo + db * 16 + l16] = f2bf(Oc[db][rr] * inv);
  }
}

// ---------------- launcher ----------------
extern "C" void kernel_launch(void* const* d_in, const int* in_sizes, int n_in,
                              void* d_out, int out_size, void* d_ws, size_t ws_size,
                              hipStream_t stream) {
  const void* x     = d_in[0];   // [8192, 1024]  fp32 or bf16 (auto-detected)
  const void* w_qkv = d_in[1];   // [1024, 3072]
  const void* w_out = d_in[2];   // [1024, 1024]

  const size_t SZ_QKV = (size_t)8192 * 3072 * 2;
  const size_t SZ_XBF = (size_t)8192 * 1024 * 2;
  const size_t SZ_WQ  = (size_t)3072 * 1024 * 2;
  const size_t SZ_WO  = (size_t)1024 * 1024 * 2;
  const size_t SZ_ATT = (size_t)8192 * 1024 * 2;

  char* p = (char*)d_ws;
  u16* qkv   = (u16*)p; p += SZ_QKV;
  u16* wqkvT = (u16*)p; p += SZ_WQ;
  u16* woutT = (u16*)p; p += SZ_WO;
  u16* xbf   = (u16*)p; p += SZ_XBF;
  u16* attb  = (u16*)p;
  const size_t need_x   = SZ_QKV + SZ_WQ + SZ_WO + SZ_XBF;
  const bool have_x   = ws_size >= need_x;
  const bool have_att = ws_size >= need_x + SZ_ATT;

  prep<<<dim3(8192), 256, 0, stream>>>(x, w_qkv, w_out, xbf, wqkvT, woutT,
                                       have_x ? 1 : 0);

  if (have_x) {
    gemm_bt<false, false><<<dim3(24, 64), 256, 0, stream>>>(
        xbf, wqkvT, qkv, 3072, 1024, 1024, 3072, x);
  } else {
    gemm_bt<true, false><<<dim3(24, 64), 256, 0, stream>>>(
        x, wqkvT, qkv, 3072, 1024, 1024, 3072, x);
  }

  // attention: compact output when ws allows, else in-place q-channel
  u16* attp  = have_att ? attb : qkv;
  const int ldo = have_att ? 1024 : 3072;
  attn_mfma<<<dim3(32, NHEADS, 4), 256, 0, stream>>>(qkv, attp, ldo);

  gemm_bt<false, true><<<dim3(8, 64), 256, 0, stream>>>(
      attp, woutT, d_out, 1024, 1024, ldo, 1024, x);
}